// Round 15
// baseline (82.066 us; speedup 1.0000x reference)
//
#include <hip/hip_runtime.h>

#define NCLASS 100
#define HID    768
#define BATCH  512
#define SG     8
#define NP32   24      // 24 panels of 32 columns/rows
#define NZ     2       // sample-group parallelism (R14 tail killer)

// Deterministic per-class sample list (wave 0 of each block).
__device__ __forceinline__ void build_list(const int* __restrict__ y, int c,
                                           int* slist, int* scnt, int t) {
    if (t < 64) {
        int n = 0;
        for (int r = 0; r < BATCH / 64; ++r) {
            const int b = r * 64 + t;
            const bool hit = (y[b] == c);
            const unsigned long long mask = __ballot(hit);
            if (hit) slist[n + __popcll(mask & ((1ull << t) - 1ull))] = b;
            n += __popcll(mask);
        }
        if (t == 0) *scnt = n;
    }
}

// ---------------------------------------------------------------------------
// Kernel A: t[b, j] for j in 32-col panel J=[32g, 32g+32), b in class c,
// sample-groups z, z+NZ, ...
//   t_j = sum_{h<j} x_h M[h,j] + d_j x_j + 1e-3 (X - x_j), d_j=max(M[j,j],1e-3)
// Grid (NP32, NCLASS, NZ), g = 23-bx (big panels dispatch first).
// Chunks of 32 rows; chunk ci covers rows [32ci, 32ci+32); last chunk (ci=g)
// is the diagonal square, masked strict h<j. Thread map: hg = t>>3 (32 rows),
// jq = t&7 (8 col-quads). 1 float4 load + 32 FMA per thread per chunk.
// Reduction: 8-lane butterfly (bits 3,4,5) + 4-wave LDS merge.
// ---------------------------------------------------------------------------
__global__ __launch_bounds__(256, 4) void kA(
    const float* __restrict__ x, const int* __restrict__ y,
    const float* __restrict__ M, float* __restrict__ T)
{
    const int c    = blockIdx.y;
    const int g    = (NP32 - 1) - blockIdx.x;
    const int z    = blockIdx.z;
    const int t    = threadIdx.x;
    const int col0 = g * 32;
    const int nch  = g + 1;

    __shared__ int   slist[BATCH];
    __shared__ int   scnt;
    __shared__ float xs[SG][HID];        // 24 KB
    __shared__ float Xs[SG];
    __shared__ float red[4][8][4][SG];   // 4 KB
    __shared__ float dj_lds[32];

    build_list(y, c, slist, &scnt, t);
    __syncthreads();
    const int cnt = scnt;
    if (cnt <= z * SG) return;

    const float* __restrict__ Mc   = M + (size_t)c * HID * HID;
    const float* __restrict__ Mpan = Mc + col0 + (t & 7) * 4;
    const int wv = t >> 6, ln = t & 63;
    const int hg = t >> 3, jq = t & 7;

    if (t < 32) {
        const int jg = col0 + t;
        dj_lds[t] = fmaxf(Mc[(size_t)jg * HID + jg], 1e-3f);
    }

    for (int g0 = z * SG; g0 < cnt; g0 += NZ * SG) {
        const int gs = min(SG, cnt - g0);
        __syncthreads();                      // prev group done; dj_lds visible
        // stage x rows: wave wv stages samples 2wv, 2wv+1; also row-sums X
        #pragma unroll
        for (int ss = 0; ss < 2; ++ss) {
            const int s = 2 * wv + ss;
            const int b = slist[g0 + (s < gs ? s : 0)];
            const float4* xr = (const float4*)(x + (size_t)b * HID);
            const float4 v0 = xr[ln], v1 = xr[ln + 64], v2 = xr[ln + 128];
            *(float4*)&xs[s][ln * 4]       = v0;
            *(float4*)&xs[s][ln * 4 + 256] = v1;
            *(float4*)&xs[s][ln * 4 + 512] = v2;
            float pX = ((v0.x + v0.y) + (v0.z + v0.w))
                     + ((v1.x + v1.y) + (v1.z + v1.w))
                     + ((v2.x + v2.y) + (v2.z + v2.w));
            #pragma unroll
            for (int off = 32; off; off >>= 1) pX += __shfl_xor(pX, off);
            if (ln == 0) Xs[s] = pX;
        }
        __syncthreads();                      // xs, Xs visible

        float tp[4][SG];
        #pragma unroll
        for (int jj = 0; jj < 4; ++jj)
            #pragma unroll
            for (int s = 0; s < SG; ++s) tp[jj][s] = 0.f;

        for (int ci = 0; ci < nch - 1; ++ci) {    // bulk chunks: rows < col0
            const int h = ci * 32 + hg;
            const float4 mq = *(const float4*)(Mpan + (size_t)h * HID);
            #pragma unroll
            for (int s = 0; s < SG; ++s) {
                const float xv = xs[s][h];
                tp[0][s] = fmaf(xv, mq.x, tp[0][s]);
                tp[1][s] = fmaf(xv, mq.y, tp[1][s]);
                tp[2][s] = fmaf(xv, mq.z, tp[2][s]);
                tp[3][s] = fmaf(xv, mq.w, tp[3][s]);
            }
        }
        {   // diagonal 32x32 square: keep col col0+4jq+e iff 4jq+e > hg
            const int h = col0 + hg;
            float4 mq = *(const float4*)(Mpan + (size_t)h * HID);
            if (4 * jq + 0 <= hg) mq.x = 0.f;
            if (4 * jq + 1 <= hg) mq.y = 0.f;
            if (4 * jq + 2 <= hg) mq.z = 0.f;
            if (4 * jq + 3 <= hg) mq.w = 0.f;
            #pragma unroll
            for (int s = 0; s < SG; ++s) {
                const float xv = xs[s][h];
                tp[0][s] = fmaf(xv, mq.x, tp[0][s]);
                tp[1][s] = fmaf(xv, mq.y, tp[1][s]);
                tp[2][s] = fmaf(xv, mq.z, tp[2][s]);
                tp[3][s] = fmaf(xv, mq.w, tp[3][s]);
            }
        }
        // reduce the 8 hg-subgroups within each wave (lane bits 3,4,5)
        #pragma unroll
        for (int mm = 8; mm <= 32; mm <<= 1)
            #pragma unroll
            for (int jj = 0; jj < 4; ++jj)
                #pragma unroll
                for (int s = 0; s < SG; ++s)
                    tp[jj][s] += __shfl_xor(tp[jj][s], mm);
        if (ln < 8) {
            #pragma unroll
            for (int jj = 0; jj < 4; ++jj)
                #pragma unroll
                for (int s = 0; s < SG; ++s)
                    red[wv][ln][jj][s] = tp[jj][s];
        }
        __syncthreads();                      // red visible
        {   // finalize: thread t -> col j = t&31, sample s = t>>5
            const int j = t & 31, jq2 = j >> 2, jj2 = j & 3;
            const int s = t >> 5;
            const int jg = col0 + j;
            if (s < gs) {
                const float u = (red[0][jq2][jj2][s] + red[1][jq2][jj2][s])
                              + (red[2][jq2][jj2][s] + red[3][jq2][jj2][s]);
                const float xj = xs[s][jg];
                T[(size_t)slist[g0 + s] * HID + jg] =
                    u + dj_lds[j] * xj + 1e-3f * (Xs[s] - xj);
            }
        }
    }
}

// ---------------------------------------------------------------------------
// Kernel B: out[b, k] for k in 32-row panel K=[32q, 32q+32), b in class c,
// sample-groups z, z+NZ, ...
//   out_k = sum_{j>k} M[k,j] t_j + d_k t_k + 1e-3 (Tt - t_k)
// Grid (NP32, NCLASS, NZ), q = bx (q=0, biggest, dispatches first).
// Chunks of 32 cols; chunk ci covers cols [k0+32ci, k0+32ci+32); chunk 0 is
// the diagonal square, masked strict j>k. Thread map: rr = t>>3 (32 rows),
// cq = t&7 (8 col-quads). Reduction: pure 8-lane butterfly (rows are
// wave-disjoint -> no cross-wave LDS merge).
// ---------------------------------------------------------------------------
__global__ __launch_bounds__(256, 4) void kB(
    const int* __restrict__ y, const float* __restrict__ M,
    const float* __restrict__ T, float* __restrict__ out)
{
    const int c   = blockIdx.y;
    const int q   = blockIdx.x;
    const int z   = blockIdx.z;
    const int t   = threadIdx.x;
    const int k0  = q * 32;
    const int nch = NP32 - q;

    __shared__ int   slist[BATCH];
    __shared__ int   scnt;
    __shared__ float ts[SG][HID];         // 24 KB
    __shared__ float Tt[SG];
    __shared__ float ob[SG][32];
    __shared__ float dk_lds[32];

    build_list(y, c, slist, &scnt, t);
    __syncthreads();
    const int cnt = scnt;
    if (cnt <= z * SG) return;

    const float* __restrict__ Mc = M + (size_t)c * HID * HID;
    const int wv = t >> 6, ln = t & 63;
    const int rr = t >> 3, cq = t & 7;
    const float* __restrict__ Mrow = Mc + (size_t)(k0 + rr) * HID + k0 + cq * 4;

    if (t < 32) {
        const int kg = k0 + t;
        dk_lds[t] = fmaxf(Mc[(size_t)kg * HID + kg], 1e-3f);
    }

    for (int g0 = z * SG; g0 < cnt; g0 += NZ * SG) {
        const int gs = min(SG, cnt - g0);
        __syncthreads();                      // prev group done (ob reads done)
        // stage t rows: wave wv stages samples 2wv, 2wv+1; also row-sums Tt
        #pragma unroll
        for (int ss = 0; ss < 2; ++ss) {
            const int s = 2 * wv + ss;
            const int b = slist[g0 + (s < gs ? s : 0)];
            const float4* tr = (const float4*)(T + (size_t)b * HID);
            const float4 v0 = tr[ln], v1 = tr[ln + 64], v2 = tr[ln + 128];
            *(float4*)&ts[s][ln * 4]       = v0;
            *(float4*)&ts[s][ln * 4 + 256] = v1;
            *(float4*)&ts[s][ln * 4 + 512] = v2;
            float pT = ((v0.x + v0.y) + (v0.z + v0.w))
                     + ((v1.x + v1.y) + (v1.z + v1.w))
                     + ((v2.x + v2.y) + (v2.z + v2.w));
            #pragma unroll
            for (int off = 32; off; off >>= 1) pT += __shfl_xor(pT, off);
            if (ln == 0) Tt[s] = pT;
        }
        __syncthreads();                      // ts, Tt visible

        float acc[SG];
        #pragma unroll
        for (int s = 0; s < SG; ++s) acc[s] = 0.f;

        {   // chunk 0: diagonal 32x32 square, keep col cq*4+e > row rr
            float4 mq = *(const float4*)(Mrow);
            if (4 * cq + 0 <= rr) mq.x = 0.f;
            if (4 * cq + 1 <= rr) mq.y = 0.f;
            if (4 * cq + 2 <= rr) mq.z = 0.f;
            if (4 * cq + 3 <= rr) mq.w = 0.f;
            const int j0 = k0 + cq * 4;
            #pragma unroll
            for (int s = 0; s < SG; ++s) {
                const float4 tv = *(const float4*)&ts[s][j0];
                acc[s] = fmaf(mq.x, tv.x, acc[s]);
                acc[s] = fmaf(mq.y, tv.y, acc[s]);
                acc[s] = fmaf(mq.z, tv.z, acc[s]);
                acc[s] = fmaf(mq.w, tv.w, acc[s]);
            }
        }
        for (int ci = 1; ci < nch; ++ci) {    // bulk chunks: cols > all rows
            const float4 mq = *(const float4*)(Mrow + ci * 32);
            const int j0 = k0 + ci * 32 + cq * 4;
            #pragma unroll
            for (int s = 0; s < SG; ++s) {
                const float4 tv = *(const float4*)&ts[s][j0];
                acc[s] = fmaf(mq.x, tv.x, acc[s]);
                acc[s] = fmaf(mq.y, tv.y, acc[s]);
                acc[s] = fmaf(mq.z, tv.z, acc[s]);
                acc[s] = fmaf(mq.w, tv.w, acc[s]);
            }
        }
        // reduce over the 8 col-quads (lane bits 0..2)
        #pragma unroll
        for (int mm = 1; mm <= 4; mm <<= 1)
            #pragma unroll
            for (int s = 0; s < SG; ++s)
                acc[s] += __shfl_xor(acc[s], mm);
        if (cq == 0) {
            #pragma unroll
            for (int s = 0; s < SG; ++s)
                ob[s][rr] = acc[s];
        }
        __syncthreads();                      // ob visible
        {   // store: thread t -> k = k0 + (t&31), sample s = t>>5
            const int j = t & 31;
            const int k = k0 + j;
            const int s = t >> 5;
            if (s < gs) {
                const float tk = ts[s][k];
                out[(size_t)slist[g0 + s] * HID + k] =
                    ob[s][j] + dk_lds[j] * tk + 1e-3f * (Tt[s] - tk);
            }
        }
    }
}

extern "C" void kernel_launch(void* const* d_in, const int* in_sizes, int n_in,
                              void* d_out, int out_size, void* d_ws, size_t ws_size,
                              hipStream_t stream) {
    const float* x = (const float*)d_in[0];
    const int*   y = (const int*)d_in[1];
    const float* M = (const float*)d_in[2];
    float* out = (float*)d_out;
    float* T   = (float*)d_ws;   // 512 * 768 * 4 B = 1.5 MiB scratch

    kA<<<dim3(NP32, NCLASS, NZ), 256, 0, stream>>>(x, y, M, T);
    kB<<<dim3(NP32, NCLASS, NZ), 256, 0, stream>>>(y, M, T, out);
}

// Round 16
// 75.234 us; speedup vs baseline: 1.0908x; 1.0908x over previous
//
#include <hip/hip_runtime.h>

#define NCLASS 100
#define HID    768
#define BATCH  512
#define SG     8
#define NPAN   12      // 12 panels of 64 columns/rows
#define NZ     2       // sample-group parallelism (R14 tail killer)

// bf16 helpers: RNE pack, cheap unpack (shift into high half).
__device__ __forceinline__ unsigned short bf16r(float f) {
    unsigned int u = __float_as_uint(f);
    u = (u + 0x7FFFu + ((u >> 16) & 1u)) >> 16;
    return (unsigned short)u;
}
__device__ __forceinline__ ushort4 pk4(float4 v) {
    return make_ushort4(bf16r(v.x), bf16r(v.y), bf16r(v.z), bf16r(v.w));
}
__device__ __forceinline__ float bf2f(unsigned short u) {
    return __uint_as_float((unsigned int)u << 16);
}

// Deterministic per-class sample list (wave 0 of each block).
__device__ __forceinline__ void build_list(const int* __restrict__ y, int c,
                                           int* slist, int* scnt, int t) {
    if (t < 64) {
        int n = 0;
        for (int r = 0; r < BATCH / 64; ++r) {
            const int b = r * 64 + t;
            const bool hit = (y[b] == c);
            const unsigned long long mask = __ballot(hit);
            if (hit) slist[n + __popcll(mask & ((1ull << t) - 1ull))] = b;
            n += __popcll(mask);
        }
        if (t == 0) *scnt = n;
    }
}

// ---------------------------------------------------------------------------
// Kernel A (R14 structure; xs staged as bf16 -> LDS 23 KB -> ~7 blocks/CU).
// t[b,j], j in 64-col panel J=[64g,64g+64), b in class c, groups z, z+NZ,...
//   t_j = sum_{h<j} x_h M[h,j] + d_j x_j + 1e-3 (X - x_j)
// Grid (NPAN, NCLASS, NZ). Thread map: hg = t>>4, jq = t&15.
// ---------------------------------------------------------------------------
__global__ __launch_bounds__(256, 4) void kA(
    const float* __restrict__ x, const int* __restrict__ y,
    const float* __restrict__ M, float* __restrict__ T)
{
    const int c    = blockIdx.y;
    const int g    = (NPAN - 1) - blockIdx.x;   // big panels dispatch first
    const int z    = blockIdx.z;
    const int t    = threadIdx.x;
    const int col0 = g * 64;

    __shared__ int            slist[BATCH];
    __shared__ int            scnt;
    __shared__ unsigned short xs16[SG][HID];   // 12 KB (bf16)
    __shared__ float          Xs[SG];
    __shared__ float          red[4][16][4][SG];   // 8 KB
    __shared__ float          dj_lds[64];

    build_list(y, c, slist, &scnt, t);
    __syncthreads();
    const int cnt = scnt;
    if (cnt <= z * SG) return;

    const float* __restrict__ Mc = M + (size_t)c * HID * HID;
    const int wv = t >> 6, ln = t & 63;
    const int hg = t >> 4, jq = t & 15;

    if (t < 64) {
        const int jg = col0 + t;
        dj_lds[t] = fmaxf(Mc[(size_t)jg * HID + jg], 1e-3f);
    }

    for (int g0 = z * SG; g0 < cnt; g0 += NZ * SG) {
        const int gs = min(SG, cnt - g0);
        __syncthreads();                      // prev group done; dj_lds visible
        // stage x rows (bf16): wave wv stages samples 2wv, 2wv+1; fp32 row-sums
        #pragma unroll
        for (int ss = 0; ss < 2; ++ss) {
            const int s = 2 * wv + ss;
            const int b = slist[g0 + (s < gs ? s : 0)];
            const float4* xr = (const float4*)(x + (size_t)b * HID);
            const float4 v0 = xr[ln], v1 = xr[ln + 64], v2 = xr[ln + 128];
            *(ushort4*)&xs16[s][ln * 4]       = pk4(v0);
            *(ushort4*)&xs16[s][ln * 4 + 256] = pk4(v1);
            *(ushort4*)&xs16[s][ln * 4 + 512] = pk4(v2);
            float pX = ((v0.x + v0.y) + (v0.z + v0.w))
                     + ((v1.x + v1.y) + (v1.z + v1.w))
                     + ((v2.x + v2.y) + (v2.z + v2.w));
            #pragma unroll
            for (int off = 32; off; off >>= 1) pX += __shfl_xor(pX, off);
            if (ln == 0) Xs[s] = pX;
        }
        __syncthreads();                      // xs16, Xs visible

        float tp[4][SG];
        #pragma unroll
        for (int jj = 0; jj < 4; ++jj)
            #pragma unroll
            for (int s = 0; s < SG; ++s) tp[jj][s] = 0.f;

        for (int hb = 0; hb < col0; hb += 64) {   // bulk rows h < col0
            float4 ma[4];
            #pragma unroll
            for (int m = 0; m < 4; ++m)
                ma[m] = *(const float4*)(Mc + (size_t)(hb + hg + 16 * m) * HID + col0 + jq * 4);
            #pragma unroll
            for (int m = 0; m < 4; ++m) {
                const int h = hb + hg + 16 * m;
                #pragma unroll
                for (int s = 0; s < SG; ++s) {
                    const float xv = bf2f(xs16[s][h]);
                    tp[0][s] = fmaf(xv, ma[m].x, tp[0][s]);
                    tp[1][s] = fmaf(xv, ma[m].y, tp[1][s]);
                    tp[2][s] = fmaf(xv, ma[m].z, tp[2][s]);
                    tp[3][s] = fmaf(xv, ma[m].w, tp[3][s]);
                }
            }
        }
        {   // peeled diagonal 64-row square: strict h<j masks
            float4 ma[4];
            #pragma unroll
            for (int m = 0; m < 4; ++m) {
                const int hrel = hg + 16 * m;
                ma[m] = *(const float4*)(Mc + (size_t)(col0 + hrel) * HID + col0 + jq * 4);
                if (4 * jq + 0 <= hrel) ma[m].x = 0.f;
                if (4 * jq + 1 <= hrel) ma[m].y = 0.f;
                if (4 * jq + 2 <= hrel) ma[m].z = 0.f;
                if (4 * jq + 3 <= hrel) ma[m].w = 0.f;
            }
            #pragma unroll
            for (int m = 0; m < 4; ++m) {
                const int h = col0 + hg + 16 * m;
                #pragma unroll
                for (int s = 0; s < SG; ++s) {
                    const float xv = bf2f(xs16[s][h]);
                    tp[0][s] = fmaf(xv, ma[m].x, tp[0][s]);
                    tp[1][s] = fmaf(xv, ma[m].y, tp[1][s]);
                    tp[2][s] = fmaf(xv, ma[m].z, tp[2][s]);
                    tp[3][s] = fmaf(xv, ma[m].w, tp[3][s]);
                }
            }
        }
        // reduce the 4 row-groups within each wave (lane bits 4,5)
        #pragma unroll
        for (int m = 16; m <= 32; m <<= 1)
            #pragma unroll
            for (int jj = 0; jj < 4; ++jj)
                #pragma unroll
                for (int s = 0; s < SG; ++s)
                    tp[jj][s] += __shfl_xor(tp[jj][s], m);
        if (ln < 16) {
            #pragma unroll
            for (int jj = 0; jj < 4; ++jj)
                #pragma unroll
                for (int s = 0; s < SG; ++s)
                    red[wv][ln][jj][s] = tp[jj][s];
        }
        __syncthreads();                      // red visible
        {   // finalize: thread t handles col j = t&63 for 2 samples
            const int j = t & 63, jq2 = j >> 2, jj2 = j & 3;
            const int jg = col0 + j;
            #pragma unroll
            for (int ss = 0; ss < 2; ++ss) {
                const int s = (t >> 6) * 2 + ss;
                if (s < gs) {
                    const float u = (red[0][jq2][jj2][s] + red[1][jq2][jj2][s])
                                  + (red[2][jq2][jj2][s] + red[3][jq2][jj2][s]);
                    const float xj = bf2f(xs16[s][jg]);
                    T[(size_t)slist[g0 + s] * HID + jg] =
                        u + dj_lds[j] * xj + 1e-3f * (Xs[s] - xj);
                }
            }
        }
    }
}

// ---------------------------------------------------------------------------
// Kernel B (R14 structure; ts staged as bf16 -> LDS 17 KB -> ~8 blocks/CU).
// out[b,k], k in 64-row panel K=[64q,64q+64), b in class c, groups z, z+NZ,...
//   out_k = sum_{j>k} M[k,j] t_j + d_k t_k + 1e-3 (Tt - t_k)
// Grid (NPAN, NCLASS, NZ). Thread map: kr = t>>4, cg = t&15.
// ---------------------------------------------------------------------------
__global__ __launch_bounds__(256, 4) void kB(
    const int* __restrict__ y, const float* __restrict__ M,
    const float* __restrict__ T, float* __restrict__ out)
{
    const int c  = blockIdx.y;
    const int q  = blockIdx.x;
    const int z  = blockIdx.z;
    const int t  = threadIdx.x;
    const int k0 = q * 64;

    __shared__ int            slist[BATCH];
    __shared__ int            scnt;
    __shared__ unsigned short ts16[SG][HID];   // 12 KB (bf16)
    __shared__ float          Tt[SG];
    __shared__ float          ob[SG][64];
    __shared__ float          dk_lds[64];

    build_list(y, c, slist, &scnt, t);
    __syncthreads();
    const int cnt = scnt;
    if (cnt <= z * SG) return;

    const float* __restrict__ Mc = M + (size_t)c * HID * HID;
    const int wv = t >> 6, ln = t & 63;
    const int kr = t >> 4, cg = t & 15;

    if (t < 64) {
        const int kg = k0 + t;
        dk_lds[t] = fmaxf(Mc[(size_t)kg * HID + kg], 1e-3f);
    }

    for (int g0 = z * SG; g0 < cnt; g0 += NZ * SG) {
        const int gs = min(SG, cnt - g0);
        __syncthreads();                      // prev group done (ob reads done)
        // stage t rows (bf16): wave wv stages samples 2wv, 2wv+1; fp32 row-sums
        #pragma unroll
        for (int ss = 0; ss < 2; ++ss) {
            const int s = 2 * wv + ss;
            const int b = slist[g0 + (s < gs ? s : 0)];
            const float4* tr = (const float4*)(T + (size_t)b * HID);
            const float4 v0 = tr[ln], v1 = tr[ln + 64], v2 = tr[ln + 128];
            *(ushort4*)&ts16[s][ln * 4]       = pk4(v0);
            *(ushort4*)&ts16[s][ln * 4 + 256] = pk4(v1);
            *(ushort4*)&ts16[s][ln * 4 + 512] = pk4(v2);
            float pT = ((v0.x + v0.y) + (v0.z + v0.w))
                     + ((v1.x + v1.y) + (v1.z + v1.w))
                     + ((v2.x + v2.y) + (v2.z + v2.w));
            #pragma unroll
            for (int off = 32; off; off >>= 1) pT += __shfl_xor(pT, off);
            if (ln == 0) Tt[s] = pT;
        }
        __syncthreads();                      // ts16, Tt visible

        float acc[4][SG];
        #pragma unroll
        for (int m = 0; m < 4; ++m)
            #pragma unroll
            for (int s = 0; s < SG; ++s) acc[m][s] = 0.f;

        for (int jb = k0; jb < HID; jb += 64) {
            const int j0 = jb + cg * 4;
            float4 mq[4];
            #pragma unroll
            for (int m = 0; m < 4; ++m) {
                const int k = k0 + 16 * m + kr;
                mq[m] = *(const float4*)(Mc + (size_t)k * HID + j0);
                if (jb == k0) {               // diag-crossing chunk: keep j>k
                    if (j0 + 0 <= k) mq[m].x = 0.f;
                    if (j0 + 1 <= k) mq[m].y = 0.f;
                    if (j0 + 2 <= k) mq[m].z = 0.f;
                    if (j0 + 3 <= k) mq[m].w = 0.f;
                }
            }
            #pragma unroll
            for (int s = 0; s < SG; ++s) {
                const ushort4 tu = *(const ushort4*)&ts16[s][j0];
                const float tx = bf2f(tu.x), ty = bf2f(tu.y),
                            tz = bf2f(tu.z), tw = bf2f(tu.w);
                #pragma unroll
                for (int m = 0; m < 4; ++m) {
                    acc[m][s] = fmaf(mq[m].x, tx, acc[m][s]);
                    acc[m][s] = fmaf(mq[m].y, ty, acc[m][s]);
                    acc[m][s] = fmaf(mq[m].z, tz, acc[m][s]);
                    acc[m][s] = fmaf(mq[m].w, tw, acc[m][s]);
                }
            }
        }
        // reduce over the 16 col-quads (lane bits 0..3)
        #pragma unroll
        for (int m2 = 1; m2 <= 8; m2 <<= 1)
            #pragma unroll
            for (int m = 0; m < 4; ++m)
                #pragma unroll
                for (int s = 0; s < SG; ++s)
                    acc[m][s] += __shfl_xor(acc[m][s], m2);
        if (cg == 0) {
            #pragma unroll
            for (int m = 0; m < 4; ++m)
                #pragma unroll
                for (int s = 0; s < SG; ++s)
                    ob[s][16 * m + kr] = acc[m][s];
        }
        __syncthreads();                      // ob visible
        // store: thread t handles k = k0 + (t&63) for 2 samples
        {
            const int j = t & 63;
            const int k = k0 + j;
            #pragma unroll
            for (int ss = 0; ss < 2; ++ss) {
                const int s = (t >> 6) * 2 + ss;
                if (s < gs) {
                    const float tk = bf2f(ts16[s][k]);
                    out[(size_t)slist[g0 + s] * HID + k] =
                        ob[s][j] + dk_lds[j] * tk + 1e-3f * (Tt[s] - tk);
                }
            }
        }
    }
}

extern "C" void kernel_launch(void* const* d_in, const int* in_sizes, int n_in,
                              void* d_out, int out_size, void* d_ws, size_t ws_size,
                              hipStream_t stream) {
    const float* x = (const float*)d_in[0];
    const int*   y = (const int*)d_in[1];
    const float* M = (const float*)d_in[2];
    float* out = (float*)d_out;
    float* T   = (float*)d_ws;   // 512 * 768 * 4 B = 1.5 MiB scratch

    kA<<<dim3(NPAN, NCLASS, NZ), 256, 0, stream>>>(x, y, M, T);
    kB<<<dim3(NPAN, NCLASS, NZ), 256, 0, stream>>>(y, M, T, out);
}